// Round 1
// baseline (2219.362 us; speedup 1.0000x reference)
//
#include <hip/hip_runtime.h>
#include <hip/hip_bf16.h>
#include <math.h>

// Problem constants
#define BB   8
#define CIN  256
#define HH   64
#define WW   64
#define KK   9
#define OMC  27          // 3*K offset/mask channels
#define HW   (HH*WW)

// ---------------------------------------------------------------------------
// Kernel 1: om = conv3x3(x, w_om) + b_om     (B,27,H,W)
// One block per (b,h). 256 threads: w = t&63, cog = t>>6 (4 channel groups).
// x rows and weight chunk staged in LDS; weight reads wave-uniform.
// ---------------------------------------------------------------------------
__global__ __launch_bounds__(256) void om_conv_kernel(
    const float* __restrict__ x, const float* __restrict__ w_om,
    const float* __restrict__ b_om, float* __restrict__ om)
{
    const int bh = blockIdx.x;
    const int b  = bh >> 6;
    const int h  = bh & 63;
    const int t  = threadIdx.x;
    const int w  = t & 63;
    const int cog = t >> 6;          // 0..3

    __shared__ float lx[16][3][66];          // [c][kh][w+1], 12.7 KB
    __shared__ float lw[OMC * 16 * 9];       // [co][c][k],   15.6 KB

    float acc[7];
#pragma unroll
    for (int j = 0; j < 7; ++j) acc[j] = 0.f;

    const float* xb = x + (size_t)b * CIN * HW;

    for (int c0 = 0; c0 < CIN; c0 += 16) {
        // stage x: 16 channels x 3 rows x 66 cols (zero-padded halo)
        for (int e = t; e < 16 * 3 * 66; e += 256) {
            int c  = e / (3 * 66);
            int r  = e % (3 * 66);
            int kh = r / 66;
            int wi = r % 66;                 // stored col = wi-1
            int hy = h - 1 + kh;
            int wx = wi - 1;
            float v = 0.f;
            if (hy >= 0 && hy < HH && wx >= 0 && wx < WW)
                v = xb[((c0 + c) * HH + hy) * WW + wx];
            lx[c][kh][wi] = v;
        }
        // stage weights: 27 co x 16 c x 9 k
        for (int e = t; e < OMC * 16 * 9; e += 256) {
            int co = e / 144;
            int r  = e % 144;                // c*9 + k
            lw[e] = w_om[co * (CIN * 9) + c0 * 9 + r];
        }
        __syncthreads();

        for (int c = 0; c < 16; ++c) {
#pragma unroll
            for (int kh = 0; kh < 3; ++kh) {
#pragma unroll
                for (int kw = 0; kw < 3; ++kw) {
                    float xv = lx[c][kh][w + kw];
                    int k = kh * 3 + kw;
#pragma unroll
                    for (int j = 0; j < 7; ++j) {
                        int co = cog + 4 * j;
                        if (co < OMC)
                            acc[j] += xv * lw[co * 144 + c * 9 + k];
                    }
                }
            }
        }
        __syncthreads();
    }

#pragma unroll
    for (int j = 0; j < 7; ++j) {
        int co = cog + 4 * j;
        if (co < OMC)
            om[((b * OMC + co) * HH + h) * WW + w] = acc[j] + b_om[co];
    }
}

// ---------------------------------------------------------------------------
// Kernel 2: bilinear-sample + mask + implicit GEMM
// One block per (b, h, 8-pixel w-tile). 256 threads.
// Phase A: thread = input channel c; gather 72 (p,k) bilinear samples to LDS.
// Phase B: thread = output channel o; acc[8] over ck=0..2303 with float4
//          weight stream and LDS-broadcast sample reads.
// ---------------------------------------------------------------------------
__global__ __launch_bounds__(256) void deform_gemm_kernel(
    const float* __restrict__ x, const float* __restrict__ om,
    const float* __restrict__ w_dc, const float* __restrict__ b_dc,
    float* __restrict__ out)
{
    const int bid = blockIdx.x;              // b*512 + h*8 + wt
    const int b   = bid >> 9;
    const int h   = (bid >> 3) & 63;
    const int w0  = (bid & 7) * 8;
    const int t   = threadIdx.x;

    __shared__ __align__(16) float s_samp[8 * 2304];   // [p][c*9+k], 73.7 KB
    __shared__ float s_wy1[72], s_wx1[72], s_m[72];
    __shared__ int   s_y0[72], s_x0[72];

    if (t < 72) {
        int p = t / 9, k = t % 9;
        int w = w0 + p;
        const float* omb = om + (size_t)b * OMC * HW + h * WW + w;
        float dy = omb[(2 * k) * HW];
        float dx = omb[(2 * k + 1) * HW];
        float mv = omb[(18 + k) * HW];
        mv = 1.f / (1.f + expf(-mv));
        float py = (float)(h - 1 + k / 3) + dy;
        float px = (float)(w - 1 + k % 3) + dx;
        float y0f = floorf(py), x0f = floorf(px);
        s_wy1[t] = py - y0f;
        s_wx1[t] = px - x0f;
        s_y0[t]  = (int)y0f;
        s_x0[t]  = (int)x0f;
        s_m[t]   = mv;
    }
    __syncthreads();

    // ---- Phase A: gather samples ----
    {
        const int c = t;
        const float* xc = x + ((size_t)b * CIN + c) * HW;
#pragma unroll 1
        for (int i = 0; i < 72; ++i) {
            int p = i / 9;
            int y0 = s_y0[i], x0 = s_x0[i];
            float wy1 = s_wy1[i], wx1 = s_wx1[i];
            float wy0 = 1.f - wy1, wx0 = 1.f - wx1;
            int y1 = y0 + 1, x1 = x0 + 1;
            bool yv0 = (y0 >= 0) && (y0 < HH);
            bool yv1 = (y1 >= 0) && (y1 < HH);
            bool xv0 = (x0 >= 0) && (x0 < WW);
            bool xv1 = (x1 >= 0) && (x1 < WW);
            int yc0 = min(max(y0, 0), HH - 1);
            int yc1 = min(max(y1, 0), HH - 1);
            int xc0 = min(max(x0, 0), WW - 1);
            int xc1 = min(max(x1, 0), WW - 1);
            float v00 = (yv0 && xv0) ? xc[yc0 * WW + xc0] : 0.f;
            float v01 = (yv0 && xv1) ? xc[yc0 * WW + xc1] : 0.f;
            float v10 = (yv1 && xv0) ? xc[yc1 * WW + xc0] : 0.f;
            float v11 = (yv1 && xv1) ? xc[yc1 * WW + xc1] : 0.f;
            float sv = (wy0 * wx0) * v00 + (wy0 * wx1) * v01 +
                       (wy1 * wx0) * v10 + (wy1 * wx1) * v11;
            // i = p*9 + k  ->  ck = c*9 + k
            int k = i - p * 9;
            s_samp[p * 2304 + c * 9 + k] = sv * s_m[i];
        }
    }
    __syncthreads();

    // ---- Phase B: out[o, 8 pixels] = W[o,:] . samp[:, p] ----
    {
        const int o = t;
        float acc[8];
#pragma unroll
        for (int p = 0; p < 8; ++p) acc[p] = 0.f;

        const float4* wp4 = reinterpret_cast<const float4*>(w_dc + (size_t)o * 2304);
        for (int q = 0; q < 576; ++q) {
            float4 wv = wp4[q];
#pragma unroll
            for (int p = 0; p < 8; ++p) {
                const float4 sv = *reinterpret_cast<const float4*>(&s_samp[p * 2304 + q * 4]);
                acc[p] += wv.x * sv.x + wv.y * sv.y + wv.z * sv.z + wv.w * sv.w;
            }
        }
        float bo = b_dc[o];
#pragma unroll
        for (int p = 0; p < 8; ++p)
            out[((size_t)(b * 256 + o) * HH + h) * WW + w0 + p] = acc[p] + bo;
    }
}

extern "C" void kernel_launch(void* const* d_in, const int* in_sizes, int n_in,
                              void* d_out, int out_size, void* d_ws, size_t ws_size,
                              hipStream_t stream) {
    const float* x    = (const float*)d_in[0];
    const float* w_om = (const float*)d_in[1];
    const float* b_om = (const float*)d_in[2];
    const float* w_dc = (const float*)d_in[3];
    const float* b_dc = (const float*)d_in[4];
    float* out = (float*)d_out;
    float* om  = (float*)d_ws;               // 8*27*64*64 fp32 = 3.54 MB scratch

    om_conv_kernel<<<BB * HH, 256, 0, stream>>>(x, w_om, b_om, om);
    deform_gemm_kernel<<<BB * HH * (WW / 8), 256, 0, stream>>>(x, om, w_dc, b_dc, out);
}

// Round 2
// 732.991 us; speedup vs baseline: 3.0278x; 3.0278x over previous
//
#include <hip/hip_runtime.h>
#include <hip/hip_bf16.h>
#include <math.h>

// Problem constants
#define BB   8
#define CIN  256
#define HH   64
#define WW   64
#define KK   9
#define OMC  27          // 3*K offset/mask channels
#define HW   (HH*WW)
#define KTOT (CIN*KK)    // 2304 GEMM K
#define SPITCH 296       // LDS sample row pitch in halves (288 + 8 pad)

typedef short bf16x8 __attribute__((ext_vector_type(8)));
typedef float f32x4  __attribute__((ext_vector_type(4)));

__device__ __forceinline__ unsigned short f2bf(float f) {
    union { float f; unsigned int u; } v; v.f = f;
    unsigned int r = v.u + 0x7FFFu + ((v.u >> 16) & 1u);   // RNE
    return (unsigned short)(r >> 16);
}

// ---------------------------------------------------------------------------
// Kernel 0: convert w_dc (fp32, [o][k] with k = c*9+tap) to bf16, swizzled
// wA[(k>>3)][o][k&7]  so an MFMA A-frag load is 16B contiguous per lane.
// ---------------------------------------------------------------------------
__global__ __launch_bounds__(256) void wprep_kernel(
    const float* __restrict__ w_dc, unsigned short* __restrict__ wA)
{
    int e = blockIdx.x * 256 + threadIdx.x;          // 256*2304 elements
    int o = e / KTOT;
    int k = e - o * KTOT;
    wA[((size_t)(k >> 3) * 256 + o) * 8 + (k & 7)] = f2bf(w_dc[e]);
}

// ---------------------------------------------------------------------------
// Kernel 1: om = conv3x3(x, w_om) + b_om     (B,27,H,W)   [unchanged fp32]
// ---------------------------------------------------------------------------
__global__ __launch_bounds__(256) void om_conv_kernel(
    const float* __restrict__ x, const float* __restrict__ w_om,
    const float* __restrict__ b_om, float* __restrict__ om)
{
    const int bh = blockIdx.x;
    const int b  = bh >> 6;
    const int h  = bh & 63;
    const int t  = threadIdx.x;
    const int w  = t & 63;
    const int cog = t >> 6;          // 0..3

    __shared__ float lx[16][3][66];
    __shared__ float lw[OMC * 16 * 9];

    float acc[7];
#pragma unroll
    for (int j = 0; j < 7; ++j) acc[j] = 0.f;

    const float* xb = x + (size_t)b * CIN * HW;

    for (int c0 = 0; c0 < CIN; c0 += 16) {
        for (int e = t; e < 16 * 3 * 66; e += 256) {
            int c  = e / (3 * 66);
            int r  = e % (3 * 66);
            int kh = r / 66;
            int wi = r % 66;
            int hy = h - 1 + kh;
            int wx = wi - 1;
            float v = 0.f;
            if (hy >= 0 && hy < HH && wx >= 0 && wx < WW)
                v = xb[((c0 + c) * HH + hy) * WW + wx];
            lx[c][kh][wi] = v;
        }
        for (int e = t; e < OMC * 16 * 9; e += 256) {
            int co = e / 144;
            int r  = e % 144;
            lw[e] = w_om[co * (CIN * 9) + c0 * 9 + r];
        }
        __syncthreads();

        for (int c = 0; c < 16; ++c) {
#pragma unroll
            for (int kh = 0; kh < 3; ++kh) {
#pragma unroll
                for (int kw = 0; kw < 3; ++kw) {
                    float xv = lx[c][kh][w + kw];
                    int k = kh * 3 + kw;
#pragma unroll
                    for (int j = 0; j < 7; ++j) {
                        int co = cog + 4 * j;
                        if (co < OMC)
                            acc[j] += xv * lw[co * 144 + c * 9 + k];
                    }
                }
            }
        }
        __syncthreads();
    }

#pragma unroll
    for (int j = 0; j < 7; ++j) {
        int co = cog + 4 * j;
        if (co < OMC)
            om[((b * OMC + co) * HH + h) * WW + w] = acc[j] + b_om[co];
    }
}

// ---------------------------------------------------------------------------
// Kernel 2: fused bilinear-gather + bf16 MFMA implicit GEMM
// Block = (b, h) row: M=256 (4 waves x 64 o), N=64 pixels, K=2304.
// K-chunk = 32 channels (288 = 9 MFMA K-steps). Samples staged bf16 in LDS.
// ---------------------------------------------------------------------------
__global__ __launch_bounds__(256) void deform_mfma_kernel(
    const float* __restrict__ x, const float* __restrict__ om,
    const unsigned short* __restrict__ wA, const float* __restrict__ b_dc,
    float* __restrict__ out)
{
    const int bid  = blockIdx.x;         // b*64 + h
    const int b    = bid >> 6;
    const int h    = bid & 63;
    const int t    = threadIdx.x;
    const int wv   = t >> 6;             // wave 0..3
    const int lane = t & 63;

    __shared__ unsigned short sS[64 * SPITCH];   // [pix][k_local], 37.9 KB
    __shared__ int    s_off[9 * 64];             // off00 per (tap,pix)
    __shared__ int    s_dpk[9 * 64];             // d01 | d10<<8
    __shared__ float4 s_w4[9 * 64];              // mask-folded bilinear weights

    // ---- per-block params: 576 (tap,pix) entries ----
    for (int e = t; e < 9 * 64; e += 256) {
        int tap = e >> 6;
        int pix = e & 63;
        const float* omb = om + (size_t)b * OMC * HW + h * WW + pix;
        float dy = omb[(2 * tap) * HW];
        float dx = omb[(2 * tap + 1) * HW];
        float mv = omb[(18 + tap) * HW];
        float m  = 1.f / (1.f + expf(-mv));
        float py = (float)(h - 1 + tap / 3) + dy;
        float px = (float)(pix - 1 + tap % 3) + dx;
        float y0f = floorf(py), x0f = floorf(px);
        float wy1 = py - y0f, wx1 = px - x0f;
        float wy0 = 1.f - wy1, wx0 = 1.f - wx1;
        int y0 = (int)y0f, x0 = (int)x0f;
        int y1 = y0 + 1, x1 = x0 + 1;
        bool yv0 = (y0 >= 0) && (y0 < HH);
        bool yv1 = (y1 >= 0) && (y1 < HH);
        bool xv0 = (x0 >= 0) && (x0 < WW);
        bool xv1 = (x1 >= 0) && (x1 < WW);
        int yc0 = min(max(y0, 0), HH - 1), yc1 = min(max(y1, 0), HH - 1);
        int xc0 = min(max(x0, 0), WW - 1), xc1 = min(max(x1, 0), WW - 1);
        float4 ww;
        ww.x = (yv0 && xv0) ? wy0 * wx0 * m : 0.f;
        ww.y = (yv0 && xv1) ? wy0 * wx1 * m : 0.f;
        ww.z = (yv1 && xv0) ? wy1 * wx0 * m : 0.f;
        ww.w = (yv1 && xv1) ? wy1 * wx1 * m : 0.f;
        s_off[e] = yc0 * WW + xc0;
        s_dpk[e] = (xc1 - xc0) | ((yc1 - yc0) * WW) << 8;
        s_w4[e]  = ww;
    }

    f32x4 acc[4][4];
#pragma unroll
    for (int i = 0; i < 4; ++i)
#pragma unroll
        for (int j = 0; j < 4; ++j)
            acc[i][j] = (f32x4)(0.f);

    const size_t xb_base = (size_t)b * CIN * HW;

    for (int ch = 0; ch < 8; ++ch) {
        __syncthreads();                  // S free (prev MFMA done) + params ready
        // ---- gather: wave wv covers channels [ch*32+wv*8, +8) x 9 taps ----
        const int cl_base = wv * 8;       // c_local base
#pragma unroll 1
        for (int tap = 0; tap < 9; ++tap) {
            int    off00 = s_off[tap * 64 + lane];
            int    dpk   = s_dpk[tap * 64 + lane];
            float4 ww    = s_w4[tap * 64 + lane];
            int d01 = dpk & 0xFF;
            int d10 = dpk >> 8;
            int d11 = d10 + d01;
#pragma unroll
            for (int ci = 0; ci < 8; ++ci) {
                int c_local = cl_base + ci;
                const float* xc = x + xb_base + (size_t)(ch * 32 + c_local) * HW;
                float v00 = xc[off00];
                float v01 = xc[off00 + d01];
                float v10 = xc[off00 + d10];
                float v11 = xc[off00 + d11];
                float sv = ww.x * v00 + ww.y * v01 + ww.z * v10 + ww.w * v11;
                sS[lane * SPITCH + c_local * 9 + tap] = f2bf(sv);
            }
        }
        __syncthreads();                  // samples ready

        // ---- MFMA: wave wv computes o in [wv*64, wv*64+64) ----
        const int kb_base = ch * 36;      // 288/8 blocks of 8 k's per chunk
        const bf16x8* wAv = reinterpret_cast<const bf16x8*>(wA);
#pragma unroll 1
        for (int ks = 0; ks < 9; ++ks) {
            bf16x8 bfr[4];
#pragma unroll
            for (int nf = 0; nf < 4; ++nf)
                bfr[nf] = *reinterpret_cast<const bf16x8*>(
                    &sS[(nf * 16 + (lane & 15)) * SPITCH + ks * 32 + (lane >> 4) * 8]);
#pragma unroll
            for (int mf = 0; mf < 4; ++mf) {
                int o  = wv * 64 + mf * 16 + (lane & 15);
                int kb = kb_base + ks * 4 + (lane >> 4);
                bf16x8 af = wAv[(size_t)kb * 256 + o];
#pragma unroll
                for (int nf = 0; nf < 4; ++nf)
                    acc[mf][nf] = __builtin_amdgcn_mfma_f32_16x16x32_bf16(
                        af, bfr[nf], acc[mf][nf], 0, 0, 0);
            }
        }
    }

    // ---- epilogue: D row = (lane>>4)*4 + reg, col = lane&15 ----
#pragma unroll
    for (int mf = 0; mf < 4; ++mf) {
#pragma unroll
        for (int r = 0; r < 4; ++r) {
            int o = wv * 64 + mf * 16 + (lane >> 4) * 4 + r;
            float bo = b_dc[o];
#pragma unroll
            for (int nf = 0; nf < 4; ++nf) {
                int pix = nf * 16 + (lane & 15);
                out[((size_t)(b * 256 + o)) * HW + h * WW + pix] = acc[mf][nf][r] + bo;
            }
        }
    }
}

extern "C" void kernel_launch(void* const* d_in, const int* in_sizes, int n_in,
                              void* d_out, int out_size, void* d_ws, size_t ws_size,
                              hipStream_t stream) {
    const float* x    = (const float*)d_in[0];
    const float* w_om = (const float*)d_in[1];
    const float* b_om = (const float*)d_in[2];
    const float* w_dc = (const float*)d_in[3];
    const float* b_dc = (const float*)d_in[4];
    float* out = (float*)d_out;

    float* om = (float*)d_ws;                             // 3,538,944 B
    unsigned short* wA = (unsigned short*)((char*)d_ws + 3538944);  // 1,179,648 B

    wprep_kernel<<<(256 * KTOT) / 256, 256, 0, stream>>>(w_dc, wA);
    om_conv_kernel<<<BB * HH, 256, 0, stream>>>(x, w_om, b_om, om);
    deform_mfma_kernel<<<BB * HH, 256, 0, stream>>>(x, om, wA, b_dc, out);
}

// Round 3
// 311.954 us; speedup vs baseline: 7.1144x; 2.3497x over previous
//
#include <hip/hip_runtime.h>
#include <hip/hip_bf16.h>
#include <math.h>

// Problem constants
#define BB   8
#define CIN  256
#define HH   64
#define WW   64
#define KK   9
#define OMC  27          // 3*K offset/mask channels
#define HW   (HH*WW)
#define KTOT (CIN*KK)    // 2304 GEMM K
#define SPITCH 296       // LDS sample row pitch in halves (288 + 8 pad)
#define XPITCH 36        // LDS x-tile channel pitch (32 + 4 pad)

typedef short bf16x8 __attribute__((ext_vector_type(8)));
typedef float f32x4  __attribute__((ext_vector_type(4)));

__device__ __forceinline__ unsigned short f2bf(float f) {
    union { float f; unsigned int u; } v; v.f = f;
    unsigned int r = v.u + 0x7FFFu + ((v.u >> 16) & 1u);   // RNE
    return (unsigned short)(r >> 16);
}

// ---------------------------------------------------------------------------
// Kernel 0a: convert w_dc (fp32, [o][k], k=c*9+tap) to bf16, swizzled
// wA[k>>3][o][k&7]  -> MFMA A-frag load = 16B contiguous per lane.
// ---------------------------------------------------------------------------
__global__ __launch_bounds__(256) void wprep_kernel(
    const float* __restrict__ w_dc, unsigned short* __restrict__ wA)
{
    int e = blockIdx.x * 256 + threadIdx.x;          // 256*2304 elements
    int o = e / KTOT;
    int k = e - o * KTOT;
    wA[((size_t)(k >> 3) * 256 + o) * 8 + (k & 7)] = f2bf(w_dc[e]);
}

// ---------------------------------------------------------------------------
// Kernel 0b: convert w_om (fp32 [27][256][9]) to bf16 padded/swizzled:
// wOmA[(((tap*8+cc)*4 + cb)*32 + o)*8 + j], k(channel) = cc*32+cb*8+j, o<32.
// ---------------------------------------------------------------------------
__global__ __launch_bounds__(256) void womprep_kernel(
    const float* __restrict__ w_om, unsigned short* __restrict__ wOmA)
{
    int e = blockIdx.x * 256 + threadIdx.x;          // 9*8*4*32*8 = 73728
    int j  = e & 7;
    int t1 = e >> 3;
    int o  = t1 & 31;
    int t2 = t1 >> 5;
    int cb = t2 & 3;
    int t3 = t2 >> 2;
    int cc = t3 & 7;
    int tap = t3 >> 3;
    int c = cc * 32 + cb * 8 + j;
    float v = (o < OMC) ? w_om[(size_t)o * KTOT + c * 9 + tap] : 0.f;
    wOmA[e] = f2bf(v);
}

// ---------------------------------------------------------------------------
// Fused kernel: om-conv MFMA prologue + bilinear-gather + bf16 MFMA GEMM
// Block = (b, h) row: M=256 (4 waves x 64 o), N=64 pixels, K=2304.
// ---------------------------------------------------------------------------
__global__ __launch_bounds__(256) void deform_mfma_kernel(
    const float* __restrict__ x, const unsigned short* __restrict__ wOmA,
    const float* __restrict__ b_om,
    const unsigned short* __restrict__ wA, const float* __restrict__ b_dc,
    float* __restrict__ out)
{
    const int bid  = blockIdx.x;         // b*64 + h
    const int b    = bid >> 6;
    const int h    = bid & 63;
    const int t    = threadIdx.x;
    const int wv   = t >> 6;             // wave 0..3
    const int lane = t & 63;

    __shared__ __align__(16) unsigned short sS[64 * SPITCH]; // 37.9 KB (overlaid below)
    __shared__ int    s_off[9 * 64];
    __shared__ int    s_dpk[9 * 64];
    __shared__ float4 s_w4[9 * 64];

    // Prologue overlays inside sS:
    //   sX  : [3][66][XPITCH] bf16 = 7128 ushorts  (bytes 0..14255)
    //   som : 27*64 fp32 = 1728 floats             (bytes 14256..21167)
    unsigned short* sX  = sS;
    float*          som = reinterpret_cast<float*>(sS + 7128);

    const size_t xb_base = (size_t)b * CIN * HW;

    // ================= om-conv prologue =================
    {
        f32x4 accOm[2];
        accOm[0] = (f32x4)(0.f);
        accOm[1] = (f32x4)(0.f);
        const bf16x8* wOmV = reinterpret_cast<const bf16x8*>(wOmA);

        for (int cc = 0; cc < 8; ++cc) {
            // stage x rows h-1..h+1, cols -1..64, 32 channels, bf16,
            // layout sX[(row*66+col)*XPITCH + c_local]
            for (int e = t; e < 3 * 66 * 32; e += 256) {
                int cl  = e / 198;            // 3*66
                int r   = e - cl * 198;
                int row = r / 66;
                int col = r - row * 66;
                int hy = h - 1 + row;
                int wx = col - 1;
                float v = 0.f;
                if (hy >= 0 && hy < HH && wx >= 0 && wx < WW)
                    v = x[xb_base + (size_t)(cc * 32 + cl) * HW + hy * WW + wx];
                sX[(row * 66 + col) * XPITCH + cl] = f2bf(v);
            }
            __syncthreads();

            // MFMA: wave wv handles N-frag wv (pixels wv*16 + lane&15)
            const int p = wv * 16 + (lane & 15);
            const int ksub = (lane >> 4);         // k sub-block (8 channels)
#pragma unroll
            for (int tap = 0; tap < 9; ++tap) {
                int kh = tap / 3, kw = tap % 3;
                bf16x8 bf = *reinterpret_cast<const bf16x8*>(
                    &sX[(kh * 66 + p + kw) * XPITCH + ksub * 8]);
#pragma unroll
                for (int mf = 0; mf < 2; ++mf) {
                    bf16x8 af = wOmV[(((tap * 8 + cc) * 4 + ksub) * 32)
                                     + mf * 16 + (lane & 15)];
                    accOm[mf] = __builtin_amdgcn_mfma_f32_16x16x32_bf16(
                        af, bf, accOm[mf], 0, 0, 0);
                }
            }
            __syncthreads();
        }

        // write om results to LDS som[ch][pix]
#pragma unroll
        for (int mf = 0; mf < 2; ++mf) {
#pragma unroll
            for (int r = 0; r < 4; ++r) {
                int o = mf * 16 + (lane >> 4) * 4 + r;
                if (o < OMC) {
                    int pix = wv * 16 + (lane & 15);
                    som[o * 64 + pix] = accOm[mf][r] + b_om[o];
                }
            }
        }
    }
    __syncthreads();

    // ================= offset/mask params from som =================
    for (int e = t; e < 9 * 64; e += 256) {
        int tap = e >> 6;
        int pix = e & 63;
        float dy = som[(2 * tap) * 64 + pix];
        float dx = som[(2 * tap + 1) * 64 + pix];
        float mv = som[(18 + tap) * 64 + pix];
        float m  = 1.f / (1.f + expf(-mv));
        float py = (float)(h - 1 + tap / 3) + dy;
        float px = (float)(pix - 1 + tap % 3) + dx;
        float y0f = floorf(py), x0f = floorf(px);
        float wy1 = py - y0f, wx1 = px - x0f;
        float wy0 = 1.f - wy1, wx0 = 1.f - wx1;
        int y0 = (int)y0f, x0 = (int)x0f;
        int y1 = y0 + 1, x1 = x0 + 1;
        bool yv0 = (y0 >= 0) && (y0 < HH);
        bool yv1 = (y1 >= 0) && (y1 < HH);
        bool xv0 = (x0 >= 0) && (x0 < WW);
        bool xv1 = (x1 >= 0) && (x1 < WW);
        int yc0 = min(max(y0, 0), HH - 1), yc1 = min(max(y1, 0), HH - 1);
        int xc0 = min(max(x0, 0), WW - 1), xc1 = min(max(x1, 0), WW - 1);
        float4 ww;
        ww.x = (yv0 && xv0) ? wy0 * wx0 * m : 0.f;
        ww.y = (yv0 && xv1) ? wy0 * wx1 * m : 0.f;
        ww.z = (yv1 && xv0) ? wy1 * wx0 * m : 0.f;
        ww.w = (yv1 && xv1) ? wy1 * wx1 * m : 0.f;
        s_off[e] = yc0 * WW + xc0;
        s_dpk[e] = (xc1 - xc0) | ((yc1 - yc0) * WW) << 8;
        s_w4[e]  = ww;
    }

    // ================= main deform GEMM =================
    f32x4 acc[4][4];
#pragma unroll
    for (int i = 0; i < 4; ++i)
#pragma unroll
        for (int j = 0; j < 4; ++j)
            acc[i][j] = (f32x4)(0.f);

    for (int ch = 0; ch < 8; ++ch) {
        __syncthreads();                  // S free (prev MFMA done) + params ready
        // ---- gather: wave wv covers channels [ch*32+wv*8, +8) x 9 taps ----
        const int cl_base = wv * 8;
#pragma unroll 1
        for (int tap = 0; tap < 9; ++tap) {
            int    off00 = s_off[tap * 64 + lane];
            int    dpk   = s_dpk[tap * 64 + lane];
            float4 ww    = s_w4[tap * 64 + lane];
            int d01 = dpk & 0xFF;
            int d10 = dpk >> 8;
            int d11 = d10 + d01;
#pragma unroll
            for (int ci = 0; ci < 8; ++ci) {
                int c_local = cl_base + ci;
                const float* xc = x + xb_base + (size_t)(ch * 32 + c_local) * HW;
                float v00 = xc[off00];
                float v01 = xc[off00 + d01];
                float v10 = xc[off00 + d10];
                float v11 = xc[off00 + d11];
                float sv = ww.x * v00 + ww.y * v01 + ww.z * v10 + ww.w * v11;
                sS[lane * SPITCH + c_local * 9 + tap] = f2bf(sv);
            }
        }
        __syncthreads();                  // samples ready

        // ---- MFMA: wave wv computes o in [wv*64, wv*64+64) ----
        const int kb_base = ch * 36;
        const bf16x8* wAv = reinterpret_cast<const bf16x8*>(wA);
#pragma unroll 1
        for (int ks = 0; ks < 9; ++ks) {
            bf16x8 bfr[4];
#pragma unroll
            for (int nf = 0; nf < 4; ++nf)
                bfr[nf] = *reinterpret_cast<const bf16x8*>(
                    &sS[(nf * 16 + (lane & 15)) * SPITCH + ks * 32 + (lane >> 4) * 8]);
#pragma unroll
            for (int mf = 0; mf < 4; ++mf) {
                int o  = wv * 64 + mf * 16 + (lane & 15);
                int kb = kb_base + ks * 4 + (lane >> 4);
                bf16x8 af = wAv[(size_t)kb * 256 + o];
#pragma unroll
                for (int nf = 0; nf < 4; ++nf)
                    acc[mf][nf] = __builtin_amdgcn_mfma_f32_16x16x32_bf16(
                        af, bfr[nf], acc[mf][nf], 0, 0, 0);
            }
        }
    }

    // ---- epilogue: D row = (lane>>4)*4 + reg, col = lane&15 ----
#pragma unroll
    for (int mf = 0; mf < 4; ++mf) {
#pragma unroll
        for (int r = 0; r < 4; ++r) {
            int o = wv * 64 + mf * 16 + (lane >> 4) * 4 + r;
            float bo = b_dc[o];
#pragma unroll
            for (int nf = 0; nf < 4; ++nf) {
                int pix = nf * 16 + (lane & 15);
                out[((size_t)(b * 256 + o)) * HW + h * WW + pix] = acc[mf][nf][r] + bo;
            }
        }
    }
}

extern "C" void kernel_launch(void* const* d_in, const int* in_sizes, int n_in,
                              void* d_out, int out_size, void* d_ws, size_t ws_size,
                              hipStream_t stream) {
    const float* x    = (const float*)d_in[0];
    const float* w_om = (const float*)d_in[1];
    const float* b_om = (const float*)d_in[2];
    const float* w_dc = (const float*)d_in[3];
    const float* b_dc = (const float*)d_in[4];
    float* out = (float*)d_out;

    unsigned short* wA   = (unsigned short*)d_ws;                    // 1,179,648 B
    unsigned short* wOmA = (unsigned short*)((char*)d_ws + 1179648); //   147,456 B

    wprep_kernel<<<(256 * KTOT) / 256, 256, 0, stream>>>(w_dc, wA);
    womprep_kernel<<<73728 / 256, 256, 0, stream>>>(w_om, wOmA);
    deform_mfma_kernel<<<BB * HH, 256, 0, stream>>>(x, wOmA, b_om, wA, b_dc, out);
}

// Round 4
// 288.520 us; speedup vs baseline: 7.6922x; 1.0812x over previous
//
#include <hip/hip_runtime.h>
#include <hip/hip_bf16.h>
#include <math.h>

// Problem constants
#define BB   8
#define CIN  256
#define HH   64
#define WW   64
#define KK   9
#define OMC  27          // 3*K offset/mask channels
#define HW   (HH*WW)
#define KTOT (CIN*KK)    // 2304 GEMM K
#define NPIX 32          // pixels per block (N tile)
#define SPITCH 296       // LDS sample row pitch in halves (288 + 8 pad)
#define XPITCH 40        // LDS x-tile channel pitch in halves (32 + 8 pad)

typedef short bf16x8 __attribute__((ext_vector_type(8)));
typedef float f32x4  __attribute__((ext_vector_type(4)));

__device__ __forceinline__ unsigned short f2bf(float f) {
    union { float f; unsigned int u; } v; v.f = f;
    unsigned int r = v.u + 0x7FFFu + ((v.u >> 16) & 1u);   // RNE
    return (unsigned short)(r >> 16);
}

// ---------------------------------------------------------------------------
// Kernel 0a: w_dc (fp32 [o][c*9+tap]) -> bf16 wA, TAP-MAJOR chunk-local k:
//   k' = (c>>5)*288 + tap*32 + (c&31);  wA[k'>>3][o][k'&7]
// ---------------------------------------------------------------------------
__global__ __launch_bounds__(256) void wprep_kernel(
    const float* __restrict__ w_dc, unsigned short* __restrict__ wA)
{
    int e = blockIdx.x * 256 + threadIdx.x;          // 256*2304 elements
    int o = e / KTOT;
    int k = e - o * KTOT;
    int c   = k / 9;
    int tap = k - c * 9;
    int kp  = (c >> 5) * 288 + tap * 32 + (c & 31);
    wA[((size_t)(kp >> 3) * 256 + o) * 8 + (kp & 7)] = f2bf(w_dc[e]);
}

// ---------------------------------------------------------------------------
// Kernel 0b: w_om (fp32 [27][256][9]) -> bf16 padded/swizzled:
// wOmA[(((tap*8+cc)*4 + cb)*32 + o)*8 + j], channel c = cc*32+cb*8+j, o<32pad.
// ---------------------------------------------------------------------------
__global__ __launch_bounds__(256) void womprep_kernel(
    const float* __restrict__ w_om, unsigned short* __restrict__ wOmA)
{
    int e = blockIdx.x * 256 + threadIdx.x;          // 73728
    int j  = e & 7;
    int t1 = e >> 3;
    int o  = t1 & 31;
    int t2 = t1 >> 5;
    int cb = t2 & 3;
    int t3 = t2 >> 2;
    int cc = t3 & 7;
    int tap = t3 >> 3;
    int c = cc * 32 + cb * 8 + j;
    float v = (o < OMC) ? w_om[(size_t)o * KTOT + c * 9 + tap] : 0.f;
    wOmA[e] = f2bf(v);
}

// ---------------------------------------------------------------------------
// Fused kernel: om-conv MFMA prologue + bilinear gather + bf16 MFMA GEMM
// Block = (b, h, w-half): M=256 (4 waves x 64 o), N=32 pixels, K=2304.
// Grid = 1024 blocks -> 4 blocks/CU; LDS 25.9 KB.
// ---------------------------------------------------------------------------
__global__ __launch_bounds__(256) void deform_mfma_kernel(
    const float* __restrict__ x, const unsigned short* __restrict__ wOmA,
    const float* __restrict__ b_om,
    const unsigned short* __restrict__ wA, const float* __restrict__ b_dc,
    float* __restrict__ out)
{
    const int bid  = blockIdx.x;         // b*128 + h*2 + wt
    const int b    = bid >> 7;
    const int h    = (bid >> 1) & 63;
    const int w0   = (bid & 1) * NPIX;
    const int t    = threadIdx.x;
    const int wv   = t >> 6;             // wave 0..3
    const int lane = t & 63;
    const int lq   = lane >> 4;          // k-quarter
    const int lm   = lane & 15;

    __shared__ __align__(16) unsigned short sS[NPIX * SPITCH]; // 18.9 KB
    __shared__ int    s_off[9 * NPIX];
    __shared__ int    s_dpk[9 * NPIX];
    __shared__ float4 s_w4[9 * NPIX];

    // Prologue overlays inside sS:
    //   sX  : [3][34][XPITCH] = 4080 halves   (0..4079)
    //   som : 27*32 fp32 = 864 floats          (halves 4096..5823)
    unsigned short* sX  = sS;
    float*          som = reinterpret_cast<float*>(sS + 4096);

    const size_t xb_base = (size_t)b * CIN * HW;

    // ================= om-conv prologue =================
    {
        f32x4 accOm = (f32x4)(0.f);
        const int mfp = wv >> 1;         // M-frag (o block of 16)
        const int nfp = wv & 1;          // N-frag (pixel block of 16)
        const int p   = nfp * 16 + lm;   // pixel 0..31
        const bf16x8* wOmV = reinterpret_cast<const bf16x8*>(wOmA);

        for (int cc = 0; cc < 8; ++cc) {
            // stage rows h-1..h+1, cols w0-1..w0+32, 32 ch, bf16
            for (int e = t; e < 3 * 34 * 32; e += 256) {
                int cl  = e / 102;            // 3*34
                int r   = e - cl * 102;
                int row = r / 34;
                int col = r - row * 34;
                int hy = h - 1 + row;
                int wx = w0 - 1 + col;
                float v = 0.f;
                if (hy >= 0 && hy < HH && wx >= 0 && wx < WW)
                    v = x[xb_base + (size_t)(cc * 32 + cl) * HW + hy * WW + wx];
                sX[(row * 34 + col) * XPITCH + cl] = f2bf(v);
            }
            __syncthreads();

#pragma unroll
            for (int tap = 0; tap < 9; ++tap) {
                int kh = tap / 3, kw = tap % 3;
                bf16x8 bf = *reinterpret_cast<const bf16x8*>(
                    &sX[(kh * 34 + p + kw) * XPITCH + lq * 8]);
                bf16x8 af = wOmV[(((tap * 8 + cc) * 4 + lq) * 32) + mfp * 16 + lm];
                accOm = __builtin_amdgcn_mfma_f32_16x16x32_bf16(af, bf, accOm, 0, 0, 0);
            }
            __syncthreads();
        }

#pragma unroll
        for (int r = 0; r < 4; ++r) {
            int o = mfp * 16 + lq * 4 + r;
            if (o < OMC)
                som[o * NPIX + p] = accOm[r] + b_om[o];
        }
    }
    __syncthreads();

    // ================= offset/mask params from som =================
    for (int e = t; e < 9 * NPIX; e += 256) {
        int tap = e >> 5;
        int pix = e & 31;
        float dy = som[(2 * tap) * NPIX + pix];
        float dx = som[(2 * tap + 1) * NPIX + pix];
        float mv = som[(18 + tap) * NPIX + pix];
        float m  = 1.f / (1.f + expf(-mv));
        float py = (float)(h - 1 + tap / 3) + dy;
        float px = (float)(w0 + pix - 1 + tap % 3) + dx;
        float y0f = floorf(py), x0f = floorf(px);
        float wy1 = py - y0f, wx1 = px - x0f;
        float wy0 = 1.f - wy1, wx0 = 1.f - wx1;
        int y0 = (int)y0f, x0 = (int)x0f;
        int y1 = y0 + 1, x1 = x0 + 1;
        bool yv0 = (y0 >= 0) && (y0 < HH);
        bool yv1 = (y1 >= 0) && (y1 < HH);
        bool xv0 = (x0 >= 0) && (x0 < WW);
        bool xv1 = (x1 >= 0) && (x1 < WW);
        int yc0 = min(max(y0, 0), HH - 1), yc1 = min(max(y1, 0), HH - 1);
        int xc0 = min(max(x0, 0), WW - 1), xc1 = min(max(x1, 0), WW - 1);
        float4 ww;
        ww.x = (yv0 && xv0) ? wy0 * wx0 * m : 0.f;
        ww.y = (yv0 && xv1) ? wy0 * wx1 * m : 0.f;
        ww.z = (yv1 && xv0) ? wy1 * wx0 * m : 0.f;
        ww.w = (yv1 && xv1) ? wy1 * wx1 * m : 0.f;
        s_off[e] = yc0 * WW + xc0;
        s_dpk[e] = (xc1 - xc0) | ((yc1 - yc0) * WW) << 8;
        s_w4[e]  = ww;
    }

    // ================= main deform GEMM =================
    f32x4 acc[4][2];
#pragma unroll
    for (int i = 0; i < 4; ++i)
#pragma unroll
        for (int j = 0; j < 2; ++j)
            acc[i][j] = (f32x4)(0.f);

    const int pix = lane & 31;           // gather pixel
    const int sub = lane >> 5;           // channel sub-half

    for (int ch = 0; ch < 8; ++ch) {
        __syncthreads();                  // sS free + params ready
        // ---- gather: wave wv covers c_local in [wv*8, wv*8+8) ----
        const float* xchb = x + xb_base + (size_t)(ch * 32) * HW;
#pragma unroll 3
        for (int tap = 0; tap < 9; ++tap) {
            int    idx   = tap * NPIX + pix;
            int    off00 = s_off[idx];
            int    dpk   = s_dpk[idx];
            float4 ww    = s_w4[idx];
            int d01 = dpk & 0xFF;
            int d10 = dpk >> 8;
            int d11 = d10 + d01;
            unsigned int pk[2];
#pragma unroll
            for (int ci = 0; ci < 4; ++ci) {
                int cl = wv * 8 + sub * 4 + ci;
                const float* xc = xchb + (size_t)cl * HW;
                float v00 = xc[off00];
                float v01 = xc[off00 + d01];
                float v10 = xc[off00 + d10];
                float v11 = xc[off00 + d11];
                float sv = ww.x * v00 + ww.y * v01 + ww.z * v10 + ww.w * v11;
                unsigned int us = f2bf(sv);
                if (ci & 1) pk[ci >> 1] |= us << 16;
                else        pk[ci >> 1]  = us;
            }
            *reinterpret_cast<uint2*>(
                &sS[pix * SPITCH + tap * 32 + wv * 8 + sub * 4]) =
                make_uint2(pk[0], pk[1]);
        }
        __syncthreads();                  // samples ready

        // ---- MFMA: wave wv computes o in [wv*64, wv*64+64) ----
        const int kb_base = ch * 36;
        const bf16x8* wAv = reinterpret_cast<const bf16x8*>(wA);
#pragma unroll 1
        for (int ks = 0; ks < 9; ++ks) {
            bf16x8 bfr[2];
#pragma unroll
            for (int nf = 0; nf < 2; ++nf)
                bfr[nf] = *reinterpret_cast<const bf16x8*>(
                    &sS[(nf * 16 + lm) * SPITCH + ks * 32 + lq * 8]);
#pragma unroll
            for (int mf = 0; mf < 4; ++mf) {
                int o  = wv * 64 + mf * 16 + lm;
                int kb = kb_base + ks * 4 + lq;
                bf16x8 af = wAv[(size_t)kb * 256 + o];
#pragma unroll
                for (int nf = 0; nf < 2; ++nf)
                    acc[mf][nf] = __builtin_amdgcn_mfma_f32_16x16x32_bf16(
                        af, bfr[nf], acc[mf][nf], 0, 0, 0);
            }
        }
    }

    // ---- epilogue: D row = lq*4 + r, col = lm ----
#pragma unroll
    for (int mf = 0; mf < 4; ++mf) {
#pragma unroll
        for (int r = 0; r < 4; ++r) {
            int o = wv * 64 + mf * 16 + lq * 4 + r;
            float bo = b_dc[o];
#pragma unroll
            for (int nf = 0; nf < 2; ++nf) {
                int p = nf * 16 + lm;
                out[((size_t)(b * 256 + o)) * HW + h * WW + w0 + p] = acc[mf][nf][r] + bo;
            }
        }
    }
}

extern "C" void kernel_launch(void* const* d_in, const int* in_sizes, int n_in,
                              void* d_out, int out_size, void* d_ws, size_t ws_size,
                              hipStream_t stream) {
    const float* x    = (const float*)d_in[0];
    const float* w_om = (const float*)d_in[1];
    const float* b_om = (const float*)d_in[2];
    const float* w_dc = (const float*)d_in[3];
    const float* b_dc = (const float*)d_in[4];
    float* out = (float*)d_out;

    unsigned short* wA   = (unsigned short*)d_ws;                    // 1,179,648 B
    unsigned short* wOmA = (unsigned short*)((char*)d_ws + 1179648); //   147,456 B

    wprep_kernel<<<(256 * KTOT) / 256, 256, 0, stream>>>(w_dc, wA);
    womprep_kernel<<<73728 / 256, 256, 0, stream>>>(w_om, wOmA);
    deform_mfma_kernel<<<BB * HH * 2, 256, 0, stream>>>(x, wOmA, b_om, wA, b_dc, out);
}